// Round 7
// baseline (1540.139 us; speedup 1.0000x reference)
//
#include <hip/hip_runtime.h>
#include <math.h>

#define BB 64
#define TT 2048
#define ADIM 384
#define NE 10    // num_embeddings == LSTM hidden
#define NG 40    // 4*NE gates
#define HD 3     // hidden_dim (codebook width)

// ---------------- workspace layout (bytes) ----------------
#define OFF_X64   0ULL
#define OFF_W64T  41943040ULL                 // ADIM*NG*8 = 122880
#define OFF_ETAB  (OFF_W64T + 122880ULL)      // NE*NG*8  = 3200 (codebook@M, NO qb)
#define OFF_ADD0  (OFF_ETAB + 3200ULL)        // NG*8     = 320  (bias, t==0)
#define OFF_ADD1  (OFF_ADD0 + 320ULL)         // NG*8     = 320  (bias+qb, t>0)
#define OFF_H     (OFF_ADD1 + 320ULL)         // BB*TT*NE*4 = 5242880
#define OFF_IDX   (OFF_H + 5242880ULL)        // BB*TT*4  = 524288
#define OFF_PART  (OFF_IDX + 524288ULL)       // 512*8

// ---------------- fast f64 helpers ----------------
__device__ __forceinline__ double rcp1(double d) {   // seed + 1 NR: err ~1 ulp
    double r = __builtin_amdgcn_rcp(d);
    double e = fma(-d, r, 1.0);
    return fma(r, e, r);
}

template<int CTRL, int RMASK>
__device__ __forceinline__ double dpp_mov_f64(double x) {
    int lo = __double2loint(x), hi = __double2hiint(x);
    lo = __builtin_amdgcn_update_dpp(lo, lo, CTRL, RMASK, 0xF, true);
    hi = __builtin_amdgcn_update_dpp(hi, hi, CTRL, RMASK, 0xF, true);
    return __hiloint2double(hi, lo);
}

// 2^(v*L): single-fma exact reduction, deg-8 Estrin (rel err ~2e-10),
// integer ldexp (exponent-field add). Valid for |v*L| < ~600.
// Validated R5/R6 (absmax 0 on full trajectory).
#define EXP2F64(res, v, L)                                                 \
    {                                                                      \
        const double MAGIC_ = 6755399441055744.0;  /* 1.5*2^52 */          \
        double sh_ = fma((v), (L), MAGIC_);                                \
        double n_  = sh_ - MAGIC_;                                         \
        int ni_ = __double2loint(sh_);                                     \
        double r_ = fma((v), (L), -n_);                                    \
        double r2_ = r_ * r_;                                              \
        double Q0_ = fma(r_, 0.6931471805599453, 1.0);                     \
        double Q1_ = fma(r_, 0.05550410866482158, 0.24022650695910072);    \
        double Q2_ = fma(r_, 0.0013333558146428443, 0.009618129107628477); \
        double Q3_ = fma(r_, 1.525273380405984e-5, 1.5403530393381606e-4); \
        double r4_ = r2_ * r2_;                                            \
        double R0_ = fma(r2_, Q1_, Q0_);                                   \
        double S1_ = fma(r2_, Q3_, Q2_);                                   \
        double S2_ = fma(r4_, 1.3215486790144307e-6, S1_);                 \
        double P_  = fma(r4_, S2_, R0_);                                   \
        int ph_ = __double2hiint(P_) + (ni_ << 20);                        \
        res = __hiloint2double(ph_, __double2loint(P_));                   \
    }

// ---------------- setup: W_ih^T (f64), Etab = codebook@M, bias tables -----
__global__ __launch_bounds__(256) void setup_kernel(
        const float* __restrict__ W_ih, const float* __restrict__ codebook,
        const float* __restrict__ qs_W, const float* __restrict__ qs_b,
        const float* __restrict__ b_ih, const float* __restrict__ b_hh,
        double* __restrict__ W64T, double* __restrict__ Etab,
        double* __restrict__ ADD0, double* __restrict__ ADD1) {
    int tid = threadIdx.x;
    if (blockIdx.x == 0) {
        if (tid < NG) {
            int k = tid;
            double M0 = 0, M1 = 0, M2 = 0, qb = 0;
            for (int a = 0; a < ADIM; ++a) {
                double w = (double)W_ih[k * ADIM + a];
                M0 = fma(w, (double)qs_W[a * HD + 0], M0);
                M1 = fma(w, (double)qs_W[a * HD + 1], M1);
                M2 = fma(w, (double)qs_W[a * HD + 2], M2);
                qb = fma(w, (double)qs_b[a], qb);
            }
            for (int i = 0; i < NE; ++i) {   // Etab WITHOUT qb (qb in ADD1)
                double e = (double)codebook[i * HD + 0] * M0;
                e = fma((double)codebook[i * HD + 1], M1, e);
                e = fma((double)codebook[i * HD + 2], M2, e);
                Etab[i * NG + k] = e;
            }
            double bias = (double)b_ih[k] + (double)b_hh[k];
            ADD0[k] = bias;        // t == 0: no qs path
            ADD1[k] = bias + qb;   // t  > 0: qs_b @ W_ih^T folded in
        }
    } else {
        int i = (blockIdx.x - 1) * 256 + tid;   // 60*256 == ADIM*NG exactly
        int a = i / NG, kk = i % NG;
        W64T[i] = (double)W_ih[kk * ADIM + a];
    }
}

// ---------------- X = hs @ W_ih.T + bias(+qb)  (f64 accumulate) -----------
__global__ __launch_bounds__(256) void gemm_kernel(
        const float* __restrict__ hs, const double* __restrict__ W64T,
        const double* __restrict__ ADD0, const double* __restrict__ ADD1,
        double* __restrict__ X64) {
    int lane = threadIdx.x & 63;
    int wv = threadIdx.x >> 6;
    int cb = __builtin_amdgcn_readfirstlane(wv * 10);   // wave-uniform col base
    long row = (long)blockIdx.x * 64 + lane;            // < 131072
    const float* xr = hs + row * ADIM;
    double acc[10];
#pragma unroll
    for (int j = 0; j < 10; ++j) acc[j] = 0.0;
    for (int a0 = 0; a0 < ADIM; a0 += 4) {
        float4 xv = *(const float4*)(xr + a0);
#pragma unroll
        for (int u = 0; u < 4; ++u) {
            double xd = (double)((&xv.x)[u]);
            const double* wp = W64T + (a0 + u) * NG + cb;  // uniform -> broadcast
#pragma unroll
            for (int j = 0; j < 10; ++j) acc[j] = fma(wp[j], xd, acc[j]);
        }
    }
    int trow = (int)(row & (TT - 1));
    double* op = X64 + row * NG + cb;
#pragma unroll
    for (int j = 0; j < 10; ++j) {
        double a0j = ADD0[cb + j], a1j = ADD1[cb + j];
        op[j] = acc[j] + (trow == 0 ? a0j : a1j);
    }
}

// ---------------- sequential recurrence: TWO batches per wave --------------
// QUAD layout: lane 4m+j holds gate j (i,f,g,o) of embedding m (m<10).
// All 4 lanes of quad m compute IDENTICAL c,h (quad-redundant) — the DPP
// argmax rotation reduce REQUIRES this redundancy (R3 bug).
// Keep the whole serial cycle on the VALU (R5: SALU ping-pong is ~2x worse).
// Two INDEPENDENT chains (batches 2*bi, 2*bi+1) interleave in one wave:
// chain A's dependency stalls are filled by chain B's instructions.
// Shared per-lane constants (whh, etab); only dynamic state duplicates.
__global__ __launch_bounds__(64) void recur_kernel(
        const double* __restrict__ X64,
        const float* __restrict__ W_hh, const double* __restrict__ Etab,
        float* __restrict__ h_out, int* __restrict__ idx_out) {
    const int k = threadIdx.x;
    const int bA = blockIdx.x * 2;
    const int bB = bA + 1;
    const int j = k & 3;                 // gate type 0..3 = i,f,g,o
    const int m = k >> 2;                // embedding index (valid < 10)
    const bool valid = (k < NG);
    const int col = valid ? (j * 10 + m) : (NG - 1);
    const bool isg = (j == 2);

    const double LOG2E = 1.4426950408889634074;
    const double Lg   = isg ? (2.0 * LOG2E) : (-LOG2E);
    const double amul = isg ? -2.0 : 1.0;
    const double aadd = isg ? 1.0 : 0.0;
    const double L2   = 2.0 * LOG2E;     // tanh(c): e^{+2|c|}

    double whh[NE];
#pragma unroll
    for (int mm = 0; mm < NE; ++mm) whh[mm] = (double)W_hh[col * NE + mm];
    double etab[NE];
#pragma unroll
    for (int i = 0; i < NE; ++i) etab[i] = Etab[i * NG + col];

    const double* XbA = X64 + (long)bA * TT * NG;
    const double* XbB = X64 + (long)bB * TT * NG;
    float* hobA = h_out + (long)bA * TT * NE;
    float* hobB = h_out + (long)bB * TT * NE;
    int* iobA = idx_out + (long)bA * TT;
    int* iobB = idx_out + (long)bB * TT;

    // prefetch rings depth 4 (t+4 overrun stays inside allocated ws)
    double xa0 = XbA[0 * NG + col], xa1 = XbA[1 * NG + col];
    double xa2 = XbA[2 * NG + col], xa3 = XbA[3 * NG + col];
    double xb0 = XbB[0 * NG + col], xb1 = XbB[1 * NG + col];
    double xb2 = XbB[2 * NG + col], xb3 = XbB[3 * NG + col];

    double haA[NE], haB[NE];
#pragma unroll
    for (int mm = 0; mm < NE; ++mm) { haA[mm] = 0.0; haB[mm] = 0.0; }
    double cA = 0.0, eselA = 0.0;
    double cB = 0.0, eselB = 0.0;

    auto step = [&](const double* __restrict__ Xb, float* __restrict__ hob,
                    int* __restrict__ iob, double& xslot, double& c,
                    double& esel, double* ha, int t) {
        double xg = xslot;
        xslot = Xb[(long)(t + 4) * NG + col];

        // gate = xg(+bias+qb folded in gemm) + esel + <h_prev, W_hh[col,:]>
        double p0 = fma(ha[1], whh[1], ha[0] * whh[0]);
        double p1 = fma(ha[3], whh[3], ha[2] * whh[2]);
        double p2 = fma(ha[5], whh[5], ha[4] * whh[4]);
        double p3 = fma(ha[7], whh[7], ha[6] * whh[6]);
        double p4 = fma(ha[9], whh[9], ha[8] * whh[8]);
        double dot = ((p0 + p1) + (p2 + p3)) + p4;
        double gate = (xg + esel) + dot;

        double e1;
        EXP2F64(e1, gate, Lg);
        double r1 = rcp1(1.0 + e1);
        double act = fma(amul, r1, aadd);

        // quad gather: broadcast ALL FOUR gates (quad-redundant c,h required)
        double fiv = dpp_mov_f64<0x00, 0xF>(act);
        double ffv = dpp_mov_f64<0x55, 0xF>(act);
        double fgv = dpp_mov_f64<0xAA, 0xF>(act);
        double fov = dpp_mov_f64<0xFF, 0xF>(act);
        c = fma(ffv, c, fiv * fgv);          // identical across quad

        double e2;
        EXP2F64(e2, fabs(c), L2);            // e^{+2|c|} in [1,inf)
        double r2 = rcp1(1.0 + e2);
        double th = fma(-2.0, r2, 1.0);      // tanh(|c|) in [0,1)
        double habs = fov * th;              // >= 0
        int hlo = __double2loint(habs);
        int hhi = __double2hiint(habs) | (__double2hiint(c) & 0x80000000);

        // argmax over m: pack (15-m) into low 4 mantissa bits, DPP max-reduce
        int klo = (hlo & ~15) | (15 - m);
        double key = __hiloint2double(hhi, klo);
        key = valid ? key : -1.0e300;
        key = fmax(key, dpp_mov_f64<0x124, 0xF>(key));  // row_ror:4
        key = fmax(key, dpp_mov_f64<0x128, 0xF>(key));  // row_ror:8
        key = fmax(key, dpp_mov_f64<0x142, 0xA>(key));  // bcast15 -> row1
        key = fmax(key, dpp_mov_f64<0x143, 0xC>(key));  // bcast31 -> rows2,3
        int slo = __builtin_amdgcn_readlane(__double2loint(key), 32);
        int s_idx = 15 - (slo & 15);         // wave-uniform argmax index

        // store h (lanes 4m, m<10) and idx (lane 40) in one masked store
        if ((k & 3) == 0 && k <= NG) {
            double hd = __hiloint2double(hhi, hlo);
            int val = valid ? __float_as_int((float)hd) : s_idx;
            int* ap = valid ? ((int*)hob + (long)t * NE + m) : (iob + t);
            *ap = val;
        }

        // broadcast h into SGPR-resident ha[] (quad-lane 4m per embedding)
#pragma unroll
        for (int mm = 0; mm < NE; ++mm) {
            int lo = __builtin_amdgcn_readlane(hlo, 4 * mm);
            int hi = __builtin_amdgcn_readlane(hhi, 4 * mm);
            ha[mm] = __hiloint2double(hi, lo);
        }
        // esel = etab[s_idx]: 4-level bit-tree select on VALU
        double a0 = (s_idx & 1) ? etab[1] : etab[0];
        double a1 = (s_idx & 1) ? etab[3] : etab[2];
        double a2 = (s_idx & 1) ? etab[5] : etab[4];
        double a3 = (s_idx & 1) ? etab[7] : etab[6];
        double a4 = (s_idx & 1) ? etab[9] : etab[8];
        double b0 = (s_idx & 2) ? a1 : a0;
        double b1 = (s_idx & 2) ? a3 : a2;
        double c0 = (s_idx & 4) ? b1 : b0;
        esel = (s_idx & 8) ? a4 : c0;
    };

    for (int t = 0; t < TT; t += 4) {
        step(XbA, hobA, iobA, xa0, cA, eselA, haA, t);
        step(XbB, hobB, iobB, xb0, cB, eselB, haB, t);
        step(XbA, hobA, iobA, xa1, cA, eselA, haA, t + 1);
        step(XbB, hobB, iobB, xb1, cB, eselB, haB, t + 1);
        step(XbA, hobA, iobA, xa2, cA, eselA, haA, t + 2);
        step(XbB, hobB, iobB, xb2, cB, eselB, haB, t + 2);
        step(XbA, hobA, iobA, xa3, cA, eselA, haA, t + 3);
        step(XbB, hobB, iobB, xb3, cB, eselB, haB, t + 3);
    }
}

// ---------------- deferred: embs gather + NLL partial sums ----------------
__global__ __launch_bounds__(256) void tail_kernel(
        const float* __restrict__ h_ws, const int* __restrict__ idx_ws,
        const int* __restrict__ inds, const float* __restrict__ codebook,
        float* __restrict__ out_embs, double* __restrict__ partials) {
    int i = blockIdx.x * 256 + threadIdx.x;   // 512*256 == 131072 exactly
    int idx = idx_ws[i];
    out_embs[i * 3 + 0] = codebook[idx * 3 + 0];
    out_embs[i * 3 + 1] = codebook[idx * 3 + 1];
    out_embs[i * 3 + 2] = codebook[idx * 3 + 2];

    const float* hp = h_ws + (long)i * NE;
    double hv[NE];
#pragma unroll
    for (int mm = 0; mm < NE; ++mm) hv[mm] = (double)hp[mm];
    double mx = hv[0];
#pragma unroll
    for (int mm = 1; mm < NE; ++mm) mx = fmax(mx, hv[mm]);
    double sdn = 0.0;
#pragma unroll
    for (int mm = 0; mm < NE; ++mm) sdn += exp(hv[mm] - mx);
    int ind = inds[i];
    double picked = (double)hp[ind] - (mx + log(sdn));

    __shared__ double red[256];
    red[threadIdx.x] = picked;
    __syncthreads();
    for (int st = 128; st > 0; st >>= 1) {
        if (threadIdx.x < st) red[threadIdx.x] += red[threadIdx.x + st];
        __syncthreads();
    }
    if (threadIdx.x == 0) partials[blockIdx.x] = red[0];
}

__global__ __launch_bounds__(256) void final_kernel(
        const double* __restrict__ partials, float* __restrict__ out_loss) {
    __shared__ double red[256];
    red[threadIdx.x] = partials[threadIdx.x] + partials[threadIdx.x + 256];
    __syncthreads();
    for (int st = 128; st > 0; st >>= 1) {
        if (threadIdx.x < st) red[threadIdx.x] += red[threadIdx.x + st];
        __syncthreads();
    }
    if (threadIdx.x == 0)
        out_loss[0] = (float)(-red[0] / (double)(BB * TT));
}

extern "C" void kernel_launch(void* const* d_in, const int* in_sizes, int n_in,
                              void* d_out, int out_size, void* d_ws, size_t ws_size,
                              hipStream_t stream) {
    const float* hs       = (const float*)d_in[0];
    const int*   inds     = (const int*)d_in[1];
    const float* codebook = (const float*)d_in[2];
    const float* W_ih     = (const float*)d_in[3];
    const float* W_hh     = (const float*)d_in[4];
    const float* b_ih     = (const float*)d_in[5];
    const float* b_hh     = (const float*)d_in[6];
    const float* qs_W     = (const float*)d_in[7];
    const float* qs_b     = (const float*)d_in[8];
    float* out = (float*)d_out;

    char* ws = (char*)d_ws;
    double* X64   = (double*)(ws + OFF_X64);
    double* W64T  = (double*)(ws + OFF_W64T);
    double* Etab  = (double*)(ws + OFF_ETAB);
    double* ADD0  = (double*)(ws + OFF_ADD0);
    double* ADD1  = (double*)(ws + OFF_ADD1);
    float*  h_ws  = (float*)(ws + OFF_H);
    int*    idx_ws= (int*)(ws + OFF_IDX);
    double* part  = (double*)(ws + OFF_PART);

    setup_kernel<<<61, 256, 0, stream>>>(W_ih, codebook, qs_W, qs_b, b_ih, b_hh,
                                         W64T, Etab, ADD0, ADD1);
    gemm_kernel<<<2048, 256, 0, stream>>>(hs, W64T, ADD0, ADD1, X64);
    recur_kernel<<<BB / 2, 64, 0, stream>>>(X64, W_hh, Etab, h_ws, idx_ws);
    tail_kernel<<<512, 256, 0, stream>>>(h_ws, idx_ws, inds, codebook, out, part);
    final_kernel<<<1, 256, 0, stream>>>(part, out + (size_t)BB * TT * HD);
}

// Round 8
// 1209.880 us; speedup vs baseline: 1.2730x; 1.2730x over previous
//
#include <hip/hip_runtime.h>
#include <math.h>

#define BB 64
#define TT 2048
#define ADIM 384
#define NE 10    // num_embeddings == LSTM hidden
#define NG 40    // 4*NE gates
#define HD 3     // hidden_dim (codebook width)

// ---------------- workspace layout (bytes) ----------------
#define OFF_X64   0ULL
#define OFF_W64T  41943040ULL                 // ADIM*NG*8 = 122880
#define OFF_ETAB  (OFF_W64T + 122880ULL)      // NE*NG*8  = 3200 (codebook@M, NO qb)
#define OFF_ADD0  (OFF_ETAB + 3200ULL)        // NG*8     = 320  (bias, t==0)
#define OFF_ADD1  (OFF_ADD0 + 320ULL)         // NG*8     = 320  (bias+qb, t>0)
#define OFF_H     (OFF_ADD1 + 320ULL)         // BB*TT*NE*4 = 5242880
#define OFF_IDX   (OFF_H + 5242880ULL)        // BB*TT*4  = 524288
#define OFF_PART  (OFF_IDX + 524288ULL)       // 512*8

// ---------------- fast f64 helpers ----------------
__device__ __forceinline__ double rcp1(double d) {   // seed + 1 NR: err ~1 ulp
    double r = __builtin_amdgcn_rcp(d);
    double e = fma(-d, r, 1.0);
    return fma(r, e, r);
}

template<int CTRL, int RMASK>
__device__ __forceinline__ double dpp_mov_f64(double x) {
    int lo = __double2loint(x), hi = __double2hiint(x);
    lo = __builtin_amdgcn_update_dpp(lo, lo, CTRL, RMASK, 0xF, true);
    hi = __builtin_amdgcn_update_dpp(hi, hi, CTRL, RMASK, 0xF, true);
    return __hiloint2double(hi, lo);
}

// 2^(v*L): single-fma exact reduction, deg-8 Estrin (rel err ~2e-10),
// integer ldexp (exponent-field add). Validated R5/R6 (absmax 0).
#define EXP2F64(res, v, L)                                                 \
    {                                                                      \
        const double MAGIC_ = 6755399441055744.0;  /* 1.5*2^52 */          \
        double sh_ = fma((v), (L), MAGIC_);                                \
        double n_  = sh_ - MAGIC_;                                         \
        int ni_ = __double2loint(sh_);                                     \
        double r_ = fma((v), (L), -n_);                                    \
        double r2_ = r_ * r_;                                              \
        double Q0_ = fma(r_, 0.6931471805599453, 1.0);                     \
        double Q1_ = fma(r_, 0.05550410866482158, 0.24022650695910072);    \
        double Q2_ = fma(r_, 0.0013333558146428443, 0.009618129107628477); \
        double Q3_ = fma(r_, 1.525273380405984e-5, 1.5403530393381606e-4); \
        double r4_ = r2_ * r2_;                                            \
        double R0_ = fma(r2_, Q1_, Q0_);                                   \
        double S1_ = fma(r2_, Q3_, Q2_);                                   \
        double S2_ = fma(r4_, 1.3215486790144307e-6, S1_);                 \
        double P_  = fma(r4_, S2_, R0_);                                   \
        int ph_ = __double2hiint(P_) + (ni_ << 20);                        \
        res = __hiloint2double(ph_, __double2loint(P_));                   \
    }

// ---------------- setup: W_ih^T (f64), Etab = codebook@M, bias tables -----
__global__ __launch_bounds__(256) void setup_kernel(
        const float* __restrict__ W_ih, const float* __restrict__ codebook,
        const float* __restrict__ qs_W, const float* __restrict__ qs_b,
        const float* __restrict__ b_ih, const float* __restrict__ b_hh,
        double* __restrict__ W64T, double* __restrict__ Etab,
        double* __restrict__ ADD0, double* __restrict__ ADD1) {
    int tid = threadIdx.x;
    if (blockIdx.x == 0) {
        if (tid < NG) {
            int k = tid;
            double M0 = 0, M1 = 0, M2 = 0, qb = 0;
            for (int a = 0; a < ADIM; ++a) {
                double w = (double)W_ih[k * ADIM + a];
                M0 = fma(w, (double)qs_W[a * HD + 0], M0);
                M1 = fma(w, (double)qs_W[a * HD + 1], M1);
                M2 = fma(w, (double)qs_W[a * HD + 2], M2);
                qb = fma(w, (double)qs_b[a], qb);
            }
            for (int i = 0; i < NE; ++i) {   // Etab WITHOUT qb (qb in ADD1)
                double e = (double)codebook[i * HD + 0] * M0;
                e = fma((double)codebook[i * HD + 1], M1, e);
                e = fma((double)codebook[i * HD + 2], M2, e);
                Etab[i * NG + k] = e;
            }
            double bias = (double)b_ih[k] + (double)b_hh[k];
            ADD0[k] = bias;        // t == 0: no qs path
            ADD1[k] = bias + qb;   // t  > 0: qs_b @ W_ih^T folded in
        }
    } else {
        int i = (blockIdx.x - 1) * 256 + tid;   // 60*256 == ADIM*NG exactly
        int a = i / NG, kk = i % NG;
        W64T[i] = (double)W_ih[kk * ADIM + a];
    }
}

// ---------------- X = hs @ W_ih.T + bias(+qb)  (f64 accumulate) -----------
__global__ __launch_bounds__(256) void gemm_kernel(
        const float* __restrict__ hs, const double* __restrict__ W64T,
        const double* __restrict__ ADD0, const double* __restrict__ ADD1,
        double* __restrict__ X64) {
    int lane = threadIdx.x & 63;
    int wv = threadIdx.x >> 6;
    int cb = __builtin_amdgcn_readfirstlane(wv * 10);   // wave-uniform col base
    long row = (long)blockIdx.x * 64 + lane;            // < 131072
    const float* xr = hs + row * ADIM;
    double acc[10];
#pragma unroll
    for (int j = 0; j < 10; ++j) acc[j] = 0.0;
    for (int a0 = 0; a0 < ADIM; a0 += 4) {
        float4 xv = *(const float4*)(xr + a0);
#pragma unroll
        for (int u = 0; u < 4; ++u) {
            double xd = (double)((&xv.x)[u]);
            const double* wp = W64T + (a0 + u) * NG + cb;  // uniform -> broadcast
#pragma unroll
            for (int j = 0; j < 10; ++j) acc[j] = fma(wp[j], xd, acc[j]);
        }
    }
    int trow = (int)(row & (TT - 1));
    double* op = X64 + row * NG + cb;
#pragma unroll
    for (int j = 0; j < 10; ++j) {
        double a0j = ADD0[cb + j], a1j = ADD1[cb + j];
        op[j] = acc[j] + (trow == 0 ? a0j : a1j);
    }
}

// ---------------- sequential recurrence: 8 waves/block, 2 waves/SIMD -------
// QUAD layout: lane 4m+j holds gate j (i,f,g,o) of embedding m (m<10).
// All 4 lanes of quad m compute IDENTICAL c,h (quad-redundant) — the DPP
// argmax rotation reduce REQUIRES this redundancy (R3 bug).
// One WAVE per chain; 8 waves/block -> 2 waves per SIMD so that one wave's
// issue bubbles (DP-pipe busy, readlane hazards) are filled by the OTHER
// wave (R7 proved same-wave interleaving fills nothing: exact 2x).
// Branchless stores: no exec-mask writes -> no exec->DPP waitstates.
__global__ __launch_bounds__(512) void recur_kernel(
        const double* __restrict__ X64,
        const float* __restrict__ W_hh, const double* __restrict__ Etab,
        char* __restrict__ ws) {
    const int k = threadIdx.x & 63;
    const int b = blockIdx.x * 8 + (threadIdx.x >> 6);   // one wave = one chain
    const int j = k & 3;                 // gate type 0..3 = i,f,g,o
    const int m = k >> 2;                // embedding index (valid < 10)
    const bool valid = (k < NG);
    const int col = valid ? (j * 10 + m) : (NG - 1);
    const bool isg = (j == 2);

    const double LOG2E = 1.4426950408889634074;
    const double Lg   = isg ? (2.0 * LOG2E) : (-LOG2E);
    const double amul = isg ? -2.0 : 1.0;
    const double aadd = isg ? 1.0 : 0.0;
    const double L2   = 2.0 * LOG2E;     // tanh(c): e^{+2|c|}

    double whh[NE];
#pragma unroll
    for (int mm = 0; mm < NE; ++mm) whh[mm] = (double)W_hh[col * NE + mm];
    double etab[NE];
#pragma unroll
    for (int i = 0; i < NE; ++i) etab[i] = Etab[i * NG + col];

    const double* Xb = (const double*)(ws + OFF_X64) + (long)b * TT * NG;

    // branchless-store setup: every lane stores 4B each step.
    // h-lanes (4m, m<10) -> h_ws; lane 40 -> idx_ws; others -> dump
    // (dump = this wave's own X64[b][0], consumed before the first store).
    const bool is_h = ((k & 3) == 0) && valid;
    const bool is_i = (k == NG);
    unsigned voff = is_h ? (unsigned)(OFF_H + ((unsigned)b * TT * NE + m) * 4u)
                  : is_i ? (unsigned)(OFF_IDX + (unsigned)b * TT * 4u)
                         : (unsigned)((unsigned)b * TT * NG * 8u);
    const unsigned vstep = is_h ? (unsigned)(NE * 4) : is_i ? 4u : 0u;

    // argmax key masks: valid lanes pack (15-m) into low 4 mantissa bits;
    // invalid lanes become -inf. Pure AND/OR with per-lane constants.
    const unsigned mA_lo = valid ? ~15u : 0u;
    const unsigned mO_lo = valid ? (unsigned)(15 - m) : 0u;
    const unsigned mA_hi = valid ? 0xFFFFFFFFu : 0u;
    const unsigned mO_hi = valid ? 0u : 0xFFF00000u;   // -inf pattern hi word

    // prefetch ring depth 4 (t+4 overrun stays inside allocated ws)
    double xs0 = Xb[0 * NG + col];
    double xs1 = Xb[1 * NG + col];
    double xs2 = Xb[2 * NG + col];
    double xs3 = Xb[3 * NG + col];

    double ha[NE];
#pragma unroll
    for (int mm = 0; mm < NE; ++mm) ha[mm] = 0.0;
    double c = 0.0, esel = 0.0;

    auto step = [&](double& xslot, int t) {
        double xg = xslot;
        xslot = Xb[(long)(t + 4) * NG + col];

        // gate = xg(+bias+qb folded in gemm) + esel + <h_prev, W_hh[col,:]>
        double p0 = fma(ha[1], whh[1], ha[0] * whh[0]);
        double p1 = fma(ha[3], whh[3], ha[2] * whh[2]);
        double p2 = fma(ha[5], whh[5], ha[4] * whh[4]);
        double p3 = fma(ha[7], whh[7], ha[6] * whh[6]);
        double p4 = fma(ha[9], whh[9], ha[8] * whh[8]);
        double dot = ((p0 + p1) + (p2 + p3)) + p4;
        double gate = (xg + esel) + dot;

        double e1;
        EXP2F64(e1, gate, Lg);
        double r1 = rcp1(1.0 + e1);
        double act = fma(amul, r1, aadd);

        // quad gather: broadcast ALL FOUR gates (quad-redundant c,h required)
        double fiv = dpp_mov_f64<0x00, 0xF>(act);
        double ffv = dpp_mov_f64<0x55, 0xF>(act);
        double fgv = dpp_mov_f64<0xAA, 0xF>(act);
        double fov = dpp_mov_f64<0xFF, 0xF>(act);
        c = fma(ffv, c, fiv * fgv);          // identical across quad

        double e2;
        EXP2F64(e2, fabs(c), L2);            // e^{+2|c|} in [1,inf)
        double r2 = rcp1(1.0 + e2);
        double th = fma(-2.0, r2, 1.0);      // tanh(|c|) in [0,1)
        double habs = fov * th;              // >= 0
        int hlo = __double2loint(habs);
        int hhi = __double2hiint(habs) | (__double2hiint(c) & 0x80000000);

        // argmax keys via AND/OR constants (no cndmask), DPP f64 max-reduce
        int klo = (int)(((unsigned)hlo & mA_lo) | mO_lo);
        int khi = (int)(((unsigned)hhi & mA_hi) | mO_hi);
        double key = __hiloint2double(khi, klo);
        key = fmax(key, dpp_mov_f64<0x124, 0xF>(key));  // row_ror:4
        key = fmax(key, dpp_mov_f64<0x128, 0xF>(key));  // row_ror:8
        key = fmax(key, dpp_mov_f64<0x142, 0xA>(key));  // bcast15 -> row1
        key = fmax(key, dpp_mov_f64<0x143, 0xC>(key));  // bcast31 -> rows2,3
        int slo = __builtin_amdgcn_readlane(__double2loint(key), 32);
        int s_idx = 15 - (slo & 15);         // wave-uniform argmax index

        // branchless store: all 64 lanes store 4B (h / idx / dump)
        float hf = (float)__hiloint2double(hhi, hlo);
        int val = is_h ? __float_as_int(hf) : s_idx;
        *(int*)(ws + voff) = val;
        voff += vstep;

        // broadcast h into SGPR-resident ha[] (quad-lane 4m per embedding)
#pragma unroll
        for (int mm = 0; mm < NE; ++mm) {
            int lo = __builtin_amdgcn_readlane(hlo, 4 * mm);
            int hi = __builtin_amdgcn_readlane(hhi, 4 * mm);
            ha[mm] = __hiloint2double(hi, lo);
        }
        // esel = etab[s_idx]: 4-level bit-tree select on VALU
        double a0 = (s_idx & 1) ? etab[1] : etab[0];
        double a1 = (s_idx & 1) ? etab[3] : etab[2];
        double a2 = (s_idx & 1) ? etab[5] : etab[4];
        double a3 = (s_idx & 1) ? etab[7] : etab[6];
        double a4 = (s_idx & 1) ? etab[9] : etab[8];
        double b0 = (s_idx & 2) ? a1 : a0;
        double b1 = (s_idx & 2) ? a3 : a2;
        double c0 = (s_idx & 4) ? b1 : b0;
        esel = (s_idx & 8) ? a4 : c0;
    };

    for (int t = 0; t < TT; t += 4) {
        step(xs0, t);
        step(xs1, t + 1);
        step(xs2, t + 2);
        step(xs3, t + 3);
    }
}

// ---------------- deferred: embs gather + NLL partial sums ----------------
__global__ __launch_bounds__(256) void tail_kernel(
        const float* __restrict__ h_ws, const int* __restrict__ idx_ws,
        const int* __restrict__ inds, const float* __restrict__ codebook,
        float* __restrict__ out_embs, double* __restrict__ partials) {
    int i = blockIdx.x * 256 + threadIdx.x;   // 512*256 == 131072 exactly
    int idx = idx_ws[i];
    out_embs[i * 3 + 0] = codebook[idx * 3 + 0];
    out_embs[i * 3 + 1] = codebook[idx * 3 + 1];
    out_embs[i * 3 + 2] = codebook[idx * 3 + 2];

    const float* hp = h_ws + (long)i * NE;
    double hv[NE];
#pragma unroll
    for (int mm = 0; mm < NE; ++mm) hv[mm] = (double)hp[mm];
    double mx = hv[0];
#pragma unroll
    for (int mm = 1; mm < NE; ++mm) mx = fmax(mx, hv[mm]);
    double sdn = 0.0;
#pragma unroll
    for (int mm = 0; mm < NE; ++mm) sdn += exp(hv[mm] - mx);
    int ind = inds[i];
    double picked = (double)hp[ind] - (mx + log(sdn));

    __shared__ double red[256];
    red[threadIdx.x] = picked;
    __syncthreads();
    for (int st = 128; st > 0; st >>= 1) {
        if (threadIdx.x < st) red[threadIdx.x] += red[threadIdx.x + st];
        __syncthreads();
    }
    if (threadIdx.x == 0) partials[blockIdx.x] = red[0];
}

__global__ __launch_bounds__(256) void final_kernel(
        const double* __restrict__ partials, float* __restrict__ out_loss) {
    __shared__ double red[256];
    red[threadIdx.x] = partials[threadIdx.x] + partials[threadIdx.x + 256];
    __syncthreads();
    for (int st = 128; st > 0; st >>= 1) {
        if (threadIdx.x < st) red[threadIdx.x] += red[threadIdx.x + st];
        __syncthreads();
    }
    if (threadIdx.x == 0)
        out_loss[0] = (float)(-red[0] / (double)(BB * TT));
}

extern "C" void kernel_launch(void* const* d_in, const int* in_sizes, int n_in,
                              void* d_out, int out_size, void* d_ws, size_t ws_size,
                              hipStream_t stream) {
    const float* hs       = (const float*)d_in[0];
    const int*   inds     = (const int*)d_in[1];
    const float* codebook = (const float*)d_in[2];
    const float* W_ih     = (const float*)d_in[3];
    const float* W_hh     = (const float*)d_in[4];
    const float* b_ih     = (const float*)d_in[5];
    const float* b_hh     = (const float*)d_in[6];
    const float* qs_W     = (const float*)d_in[7];
    const float* qs_b     = (const float*)d_in[8];
    float* out = (float*)d_out;

    char* ws = (char*)d_ws;
    double* X64   = (double*)(ws + OFF_X64);
    double* W64T  = (double*)(ws + OFF_W64T);
    double* Etab  = (double*)(ws + OFF_ETAB);
    double* ADD0  = (double*)(ws + OFF_ADD0);
    double* ADD1  = (double*)(ws + OFF_ADD1);
    float*  h_ws  = (float*)(ws + OFF_H);
    int*    idx_ws= (int*)(ws + OFF_IDX);
    double* part  = (double*)(ws + OFF_PART);

    setup_kernel<<<61, 256, 0, stream>>>(W_ih, codebook, qs_W, qs_b, b_ih, b_hh,
                                         W64T, Etab, ADD0, ADD1);
    gemm_kernel<<<2048, 256, 0, stream>>>(hs, W64T, ADD0, ADD1, X64);
    recur_kernel<<<BB / 8, 512, 0, stream>>>(X64, W_hh, Etab, ws);
    tail_kernel<<<512, 256, 0, stream>>>(h_ws, idx_ws, inds, codebook, out, part);
    final_kernel<<<1, 256, 0, stream>>>(part, out + (size_t)BB * TT * HD);
}

// Round 9
// 727.167 us; speedup vs baseline: 2.1180x; 1.6638x over previous
//
#include <hip/hip_runtime.h>
#include <math.h>

#define BB 64
#define TT 2048
#define ADIM 384
#define NE 10    // num_embeddings == LSTM hidden
#define NG 40    // 4*NE gates
#define HD 3     // hidden_dim (codebook width)

// ---------------- workspace layout (bytes) ----------------
#define OFF_X64   0ULL
#define OFF_W64T  41943040ULL                 // ADIM*NG*8 = 122880
#define OFF_ETAB  (OFF_W64T + 122880ULL)      // NE*NG*4 = 1600 (f32, codebook@M)
#define OFF_ADD0  (OFF_ETAB + 3200ULL)        // NG*8 = 320  (bias, t==0)
#define OFF_ADD1  (OFF_ADD0 + 320ULL)         // NG*8 = 320  (bias+qb, t>0)
#define OFF_H     (OFF_ADD1 + 320ULL)         // BB*TT*NE*4 = 5242880
#define OFF_IDX   (OFF_H + 5242880ULL)        // BB*TT*4 = 524288
#define OFF_PART  (OFF_IDX + 524288ULL)       // 512*8

// ---------------- fast helpers ----------------
__device__ __forceinline__ float fexp2(float x) {   // HW 2^x, ~1 ulp
    float r;
    asm("v_exp_f32 %0, %1" : "=v"(r) : "v"(x));
    return r;
}
__device__ __forceinline__ float frcp1(float d) {   // seed + 1 NR
    float r;
    asm("v_rcp_f32 %0, %1" : "=v"(r) : "v"(d));
    float e = fmaf(-d, r, 1.0f);
    return fmaf(r, e, r);
}

template<int CTRL>
__device__ __forceinline__ float dpp_mov_f32(float x) {
    int v = __float_as_int(x);
    v = __builtin_amdgcn_update_dpp(v, v, CTRL, 0xF, 0xF, true);
    return __int_as_float(v);
}

template<int CTRL, int RMASK>
__device__ __forceinline__ double dpp_mov_f64(double x) {
    int lo = __double2loint(x), hi = __double2hiint(x);
    lo = __builtin_amdgcn_update_dpp(lo, lo, CTRL, RMASK, 0xF, true);
    hi = __builtin_amdgcn_update_dpp(hi, hi, CTRL, RMASK, 0xF, true);
    return __hiloint2double(hi, lo);
}

// ---------------- setup: W_ih^T (f64), Etab32 = codebook@M, bias tables ----
__global__ __launch_bounds__(256) void setup_kernel(
        const float* __restrict__ W_ih, const float* __restrict__ codebook,
        const float* __restrict__ qs_W, const float* __restrict__ qs_b,
        const float* __restrict__ b_ih, const float* __restrict__ b_hh,
        double* __restrict__ W64T, float* __restrict__ Etab32,
        double* __restrict__ ADD0, double* __restrict__ ADD1) {
    int tid = threadIdx.x;
    if (blockIdx.x == 0) {
        if (tid < NG) {
            int k = tid;
            double M0 = 0, M1 = 0, M2 = 0, qb = 0;
            for (int a = 0; a < ADIM; ++a) {
                double w = (double)W_ih[k * ADIM + a];
                M0 = fma(w, (double)qs_W[a * HD + 0], M0);
                M1 = fma(w, (double)qs_W[a * HD + 1], M1);
                M2 = fma(w, (double)qs_W[a * HD + 2], M2);
                qb = fma(w, (double)qs_b[a], qb);
            }
            for (int i = 0; i < NE; ++i) {   // Etab WITHOUT qb (qb in ADD1)
                double e = (double)codebook[i * HD + 0] * M0;
                e = fma((double)codebook[i * HD + 1], M1, e);
                e = fma((double)codebook[i * HD + 2], M2, e);
                Etab32[i * NG + k] = (float)e;
            }
            double bias = (double)b_ih[k] + (double)b_hh[k];
            ADD0[k] = bias;        // t == 0: no qs path
            ADD1[k] = bias + qb;   // t  > 0: qs_b @ W_ih^T folded in
        }
    } else {
        int i = (blockIdx.x - 1) * 256 + tid;   // 60*256 == ADIM*NG exactly
        int a = i / NG, kk = i % NG;
        W64T[i] = (double)W_ih[kk * ADIM + a];
    }
}

// ---------------- X = hs @ W_ih.T + bias(+qb)  (f64 accumulate) -----------
__global__ __launch_bounds__(256) void gemm_kernel(
        const float* __restrict__ hs, const double* __restrict__ W64T,
        const double* __restrict__ ADD0, const double* __restrict__ ADD1,
        double* __restrict__ X64) {
    int lane = threadIdx.x & 63;
    int wv = threadIdx.x >> 6;
    int cb = __builtin_amdgcn_readfirstlane(wv * 10);   // wave-uniform col base
    long row = (long)blockIdx.x * 64 + lane;            // < 131072
    const float* xr = hs + row * ADIM;
    double acc[10];
#pragma unroll
    for (int j = 0; j < 10; ++j) acc[j] = 0.0;
    for (int a0 = 0; a0 < ADIM; a0 += 4) {
        float4 xv = *(const float4*)(xr + a0);
#pragma unroll
        for (int u = 0; u < 4; ++u) {
            double xd = (double)((&xv.x)[u]);
            const double* wp = W64T + (a0 + u) * NG + cb;  // uniform -> broadcast
#pragma unroll
            for (int j = 0; j < 10; ++j) acc[j] = fma(wp[j], xd, acc[j]);
        }
    }
    int trow = (int)(row & (TT - 1));
    double* op = X64 + row * NG + cb;
#pragma unroll
    for (int j = 0; j < 10; ++j) {
        double a0j = ADD0[cb + j], a1j = ADD1[cb + j];
        op[j] = acc[j] + (trow == 0 ? a0j : a1j);
    }
}

// ---------------- sequential recurrence: one wave per batch ----------------
// QUAD layout: lane 4m+j holds gate j (i,f,g,o) of embedding m (m<10).
// All 4 lanes of quad m compute IDENTICAL c,h (quad-redundant) — the DPP
// argmax rotation reduce REQUIRES this redundancy (R3 bug).
// f32 core (ref is numpy f32; noise same scale as already-passing f64-vs-ref),
// f64 rails: X stays f64, gate summed in f64 once; argmax keys are f64
// ((double)h + 2.0 -> positive domain so the packed tie-break index is
// monotone for both signs; index in low 4 mantissa bits = 2^-48 perturb).
// Keep everything on the VALU (R5: SALU ping-pong ~2x worse); 1 wave/SIMD
// (R8: co-residency hurts wall time).
__global__ __launch_bounds__(64) void recur_kernel(
        const double* __restrict__ X64,
        const float* __restrict__ W_hh, const float* __restrict__ Etab32,
        float* __restrict__ h_out, int* __restrict__ idx_out) {
    const int k = threadIdx.x;
    const int b = blockIdx.x;
    const int j = k & 3;                 // gate type 0..3 = i,f,g,o
    const int m = k >> 2;                // embedding index (valid < 10)
    const bool valid = (k < NG);
    const int col = valid ? (j * 10 + m) : (NG - 1);
    const bool isg = (j == 2);

    const float LOG2E = 1.44269504088896340736f;
    // i/f/o: e1 = 2^{-g*log2e} -> act = 1/(1+e1)          (amul=1, aadd=0)
    // g:     e1 = 2^{-2g*log2e} -> act = 2/(1+e1) - 1     (amul=2, aadd=-1)
    const float Lg   = isg ? (-2.0f * LOG2E) : (-LOG2E);
    const float amul = isg ? 2.0f : 1.0f;
    const float aadd = isg ? -1.0f : 0.0f;
    const float L2   = -2.0f * LOG2E;    // tanh|c|: 2/(1+2^{-2|c|log2e}) - 1

    float whh[NE];
#pragma unroll
    for (int mm = 0; mm < NE; ++mm) whh[mm] = W_hh[col * NE + mm];
    float etab[NE];
#pragma unroll
    for (int i = 0; i < NE; ++i) etab[i] = Etab32[i * NG + col];

    const double* Xb = X64 + (long)b * TT * NG;
    float* hob = h_out + (long)b * TT * NE;
    int* iob = idx_out + (long)b * TT;

    // argmax key masks: valid lanes pack (15-m) into low 4 mantissa bits of
    // the positive-domain key; invalid lanes -> -inf. Branchless AND/OR.
    const unsigned mA_lo = valid ? ~15u : 0u;
    const unsigned mO_lo = valid ? (unsigned)(15 - m) : 0u;
    const unsigned mA_hi = valid ? 0xFFFFFFFFu : 0u;
    const unsigned mO_hi = valid ? 0u : 0xFFF00000u;   // -inf hi word

    // prefetch ring depth 4 (t+4 overrun stays inside allocated ws)
    double xs0 = Xb[0 * NG + col];
    double xs1 = Xb[1 * NG + col];
    double xs2 = Xb[2 * NG + col];
    double xs3 = Xb[3 * NG + col];

    float ha[NE];
#pragma unroll
    for (int mm = 0; mm < NE; ++mm) ha[mm] = 0.0f;
    float c = 0.0f, esel = 0.0f;

    auto step = [&](double& xslot, int t) {
        double xg = xslot;
        xslot = Xb[(long)(t + 4) * NG + col];

        // f32 dot + esel; gate summed once in f64 (X precision preserved)
        float p0 = fmaf(ha[1], whh[1], ha[0] * whh[0]);
        float p1 = fmaf(ha[3], whh[3], ha[2] * whh[2]);
        float p2 = fmaf(ha[5], whh[5], ha[4] * whh[4]);
        float p3 = fmaf(ha[7], whh[7], ha[6] * whh[6]);
        float p4 = fmaf(ha[9], whh[9], ha[8] * whh[8]);
        float dotE = ((p0 + p1) + (p2 + p3)) + (p4 + esel);
        float g32 = (float)(xg + (double)dotE);

        float e1 = fexp2(g32 * Lg);          // no range reduction: |g|<~8
        float r1 = frcp1(1.0f + e1);
        float act = fmaf(amul, r1, aadd);

        // quad gather: broadcast ALL FOUR gates (quad-redundant c,h required)
        float fiv = dpp_mov_f32<0x00>(act);
        float ffv = dpp_mov_f32<0x55>(act);
        float fgv = dpp_mov_f32<0xAA>(act);
        float fov = dpp_mov_f32<0xFF>(act);
        c = fmaf(ffv, c, fiv * fgv);         // identical across quad

        float e2 = fexp2(fabsf(c) * L2);     // 2^{-2|c|log2e} in (0,1]
        float r2 = frcp1(1.0f + e2);
        float th = fmaf(2.0f, r2, -1.0f);    // tanh(|c|) in [0,1)
        float habs = fov * th;               // >= 0
        int hI = __float_as_int(habs) | (__float_as_int(c) & 0x80000000);
        float h = __int_as_float(hI);

        // f64 argmax key: (double)h + 2.0 -> (1,3) positive; pack (15-m)
        double kd = (double)h + 2.0;
        int klo = __double2loint(kd), khi = __double2hiint(kd);
        klo = (int)(((unsigned)klo & mA_lo) | mO_lo);
        khi = (int)(((unsigned)khi & mA_hi) | mO_hi);
        double key = __hiloint2double(khi, klo);
        key = fmax(key, dpp_mov_f64<0x124, 0xF>(key));  // row_ror:4
        key = fmax(key, dpp_mov_f64<0x128, 0xF>(key));  // row_ror:8
        key = fmax(key, dpp_mov_f64<0x142, 0xA>(key));  // bcast15 -> row1
        key = fmax(key, dpp_mov_f64<0x143, 0xC>(key));  // bcast31 -> rows2,3
        int slo = __builtin_amdgcn_readlane(__double2loint(key), 32);
        int s_idx = 15 - (slo & 15);         // wave-uniform argmax index

        // store h (lanes 4m, m<10) and idx (lane 40) in one masked store
        if ((k & 3) == 0 && k <= NG) {
            int val = valid ? hI : s_idx;
            int* ap = valid ? ((int*)hob + (long)t * NE + m) : (iob + t);
            *ap = val;
        }

        // broadcast h into SGPR-resident ha[] (quad-lane 4m per embedding)
#pragma unroll
        for (int mm = 0; mm < NE; ++mm)
            ha[mm] = __int_as_float(__builtin_amdgcn_readlane(hI, 4 * mm));

        // esel = etab[s_idx]: 4-level bit-tree select on VALU (f32)
        float a0 = (s_idx & 1) ? etab[1] : etab[0];
        float a1 = (s_idx & 1) ? etab[3] : etab[2];
        float a2 = (s_idx & 1) ? etab[5] : etab[4];
        float a3 = (s_idx & 1) ? etab[7] : etab[6];
        float a4 = (s_idx & 1) ? etab[9] : etab[8];
        float b0 = (s_idx & 2) ? a1 : a0;
        float b1 = (s_idx & 2) ? a3 : a2;
        float c0 = (s_idx & 4) ? b1 : b0;
        esel = (s_idx & 8) ? a4 : c0;
    };

    for (int t = 0; t < TT; t += 4) {
        step(xs0, t);
        step(xs1, t + 1);
        step(xs2, t + 2);
        step(xs3, t + 3);
    }
}

// ---------------- deferred: embs gather + NLL partial sums ----------------
__global__ __launch_bounds__(256) void tail_kernel(
        const float* __restrict__ h_ws, const int* __restrict__ idx_ws,
        const int* __restrict__ inds, const float* __restrict__ codebook,
        float* __restrict__ out_embs, double* __restrict__ partials) {
    int i = blockIdx.x * 256 + threadIdx.x;   // 512*256 == 131072 exactly
    int idx = idx_ws[i];
    out_embs[i * 3 + 0] = codebook[idx * 3 + 0];
    out_embs[i * 3 + 1] = codebook[idx * 3 + 1];
    out_embs[i * 3 + 2] = codebook[idx * 3 + 2];

    const float* hp = h_ws + (long)i * NE;
    double hv[NE];
#pragma unroll
    for (int mm = 0; mm < NE; ++mm) hv[mm] = (double)hp[mm];
    double mx = hv[0];
#pragma unroll
    for (int mm = 1; mm < NE; ++mm) mx = fmax(mx, hv[mm]);
    double sdn = 0.0;
#pragma unroll
    for (int mm = 0; mm < NE; ++mm) sdn += exp(hv[mm] - mx);
    int ind = inds[i];
    double picked = (double)hp[ind] - (mx + log(sdn));

    __shared__ double red[256];
    red[threadIdx.x] = picked;
    __syncthreads();
    for (int st = 128; st > 0; st >>= 1) {
        if (threadIdx.x < st) red[threadIdx.x] += red[threadIdx.x + st];
        __syncthreads();
    }
    if (threadIdx.x == 0) partials[blockIdx.x] = red[0];
}

__global__ __launch_bounds__(256) void final_kernel(
        const double* __restrict__ partials, float* __restrict__ out_loss) {
    __shared__ double red[256];
    red[threadIdx.x] = partials[threadIdx.x] + partials[threadIdx.x + 256];
    __syncthreads();
    for (int st = 128; st > 0; st >>= 1) {
        if (threadIdx.x < st) red[threadIdx.x] += red[threadIdx.x + st];
        __syncthreads();
    }
    if (threadIdx.x == 0)
        out_loss[0] = (float)(-red[0] / (double)(BB * TT));
}

extern "C" void kernel_launch(void* const* d_in, const int* in_sizes, int n_in,
                              void* d_out, int out_size, void* d_ws, size_t ws_size,
                              hipStream_t stream) {
    const float* hs       = (const float*)d_in[0];
    const int*   inds     = (const int*)d_in[1];
    const float* codebook = (const float*)d_in[2];
    const float* W_ih     = (const float*)d_in[3];
    const float* W_hh     = (const float*)d_in[4];
    const float* b_ih     = (const float*)d_in[5];
    const float* b_hh     = (const float*)d_in[6];
    const float* qs_W     = (const float*)d_in[7];
    const float* qs_b     = (const float*)d_in[8];
    float* out = (float*)d_out;

    char* ws = (char*)d_ws;
    double* X64   = (double*)(ws + OFF_X64);
    double* W64T  = (double*)(ws + OFF_W64T);
    float*  Etab32= (float*)(ws + OFF_ETAB);
    double* ADD0  = (double*)(ws + OFF_ADD0);
    double* ADD1  = (double*)(ws + OFF_ADD1);
    float*  h_ws  = (float*)(ws + OFF_H);
    int*    idx_ws= (int*)(ws + OFF_IDX);
    double* part  = (double*)(ws + OFF_PART);

    setup_kernel<<<61, 256, 0, stream>>>(W_ih, codebook, qs_W, qs_b, b_ih, b_hh,
                                         W64T, Etab32, ADD0, ADD1);
    gemm_kernel<<<2048, 256, 0, stream>>>(hs, W64T, ADD0, ADD1, X64);
    recur_kernel<<<BB, 64, 0, stream>>>(X64, W_hh, Etab32, h_ws, idx_ws);
    tail_kernel<<<512, 256, 0, stream>>>(h_ws, idx_ws, inds, codebook, out, part);
    final_kernel<<<1, 256, 0, stream>>>(part, out + (size_t)BB * TT * HD);
}

// Round 10
// 595.398 us; speedup vs baseline: 2.5867x; 1.2213x over previous
//
#include <hip/hip_runtime.h>
#include <math.h>

#define BB 64
#define TT 2048
#define ADIM 384
#define NE 10    // num_embeddings == LSTM hidden
#define NG 40    // 4*NE gates
#define HD 3     // hidden_dim (codebook width)

// ---------------- workspace layout (bytes) ----------------
#define OFF_X64   0ULL                        // X32: BB*TT*NG*4 = 20971520 (slack to W64T)
#define OFF_W64T  41943040ULL                 // ADIM*NG*8 = 122880
#define OFF_ETAB  (OFF_W64T + 122880ULL)      // NE*NG*4 = 1600 (f32, codebook@M)
#define OFF_ADD0  (OFF_ETAB + 3200ULL)        // NG*8 = 320  (bias, t==0)
#define OFF_ADD1  (OFF_ADD0 + 320ULL)         // NG*8 = 320  (bias+qb, t>0)
#define OFF_H     (OFF_ADD1 + 320ULL)         // BB*TT*NE*4 = 5242880
#define OFF_IDX   (OFF_H + 5242880ULL)        // BB*TT*4 = 524288
#define OFF_PART  (OFF_IDX + 524288ULL)       // 512*8
#define OFF_DUMP  (OFF_PART + 4096ULL)        // 64B dump word for garbage lanes

// ---------------- fast helpers ----------------
__device__ __forceinline__ float fexp2(float x) {   // HW 2^x, ~1 ulp
    float r;
    asm("v_exp_f32 %0, %1" : "=v"(r) : "v"(x));
    return r;
}
__device__ __forceinline__ float frcp1(float d) {   // seed + 1 NR
    float r;
    asm("v_rcp_f32 %0, %1" : "=v"(r) : "v"(d));
    float e = fmaf(-d, r, 1.0f);
    return fmaf(r, e, r);
}

template<int CTRL>
__device__ __forceinline__ float dpp_mov_f32(float x) {
    int v = __float_as_int(x);
    v = __builtin_amdgcn_update_dpp(v, v, CTRL, 0xF, 0xF, true);
    return __int_as_float(v);
}
template<int CTRL, int RMASK>
__device__ __forceinline__ unsigned dpp_mov_u32(unsigned x) {
    int v = __builtin_amdgcn_update_dpp((int)x, (int)x, CTRL, RMASK, 0xF, true);
    return (unsigned)v;
}
__device__ __forceinline__ unsigned umax2(unsigned a, unsigned b) {
    return a > b ? a : b;
}

// ---------------- setup: W_ih^T (f64), Etab32 = codebook@M, bias tables ----
__global__ __launch_bounds__(256) void setup_kernel(
        const float* __restrict__ W_ih, const float* __restrict__ codebook,
        const float* __restrict__ qs_W, const float* __restrict__ qs_b,
        const float* __restrict__ b_ih, const float* __restrict__ b_hh,
        double* __restrict__ W64T, float* __restrict__ Etab32,
        double* __restrict__ ADD0, double* __restrict__ ADD1) {
    int tid = threadIdx.x;
    if (blockIdx.x == 0) {
        if (tid < NG) {
            int k = tid;
            double M0 = 0, M1 = 0, M2 = 0, qb = 0;
            for (int a = 0; a < ADIM; ++a) {
                double w = (double)W_ih[k * ADIM + a];
                M0 = fma(w, (double)qs_W[a * HD + 0], M0);
                M1 = fma(w, (double)qs_W[a * HD + 1], M1);
                M2 = fma(w, (double)qs_W[a * HD + 2], M2);
                qb = fma(w, (double)qs_b[a], qb);
            }
            for (int i = 0; i < NE; ++i) {   // Etab WITHOUT qb (qb in ADD1)
                double e = (double)codebook[i * HD + 0] * M0;
                e = fma((double)codebook[i * HD + 1], M1, e);
                e = fma((double)codebook[i * HD + 2], M2, e);
                Etab32[i * NG + k] = (float)e;
            }
            double bias = (double)b_ih[k] + (double)b_hh[k];
            ADD0[k] = bias;        // t == 0: no qs path
            ADD1[k] = bias + qb;   // t  > 0: qs_b @ W_ih^T folded in
        }
    } else {
        int i = (blockIdx.x - 1) * 256 + tid;   // 60*256 == ADIM*NG exactly
        int a = i / NG, kk = i % NG;
        W64T[i] = (double)W_ih[kk * ADIM + a];
    }
}

// ---------------- X = hs @ W_ih.T + bias(+qb); f64 accumulate, f32 out -----
__global__ __launch_bounds__(256) void gemm_kernel(
        const float* __restrict__ hs, const double* __restrict__ W64T,
        const double* __restrict__ ADD0, const double* __restrict__ ADD1,
        float* __restrict__ X32) {
    int lane = threadIdx.x & 63;
    int wv = threadIdx.x >> 6;
    int cb = __builtin_amdgcn_readfirstlane(wv * 10);   // wave-uniform col base
    long row = (long)blockIdx.x * 64 + lane;            // < 131072
    const float* xr = hs + row * ADIM;
    double acc[10];
#pragma unroll
    for (int j = 0; j < 10; ++j) acc[j] = 0.0;
    for (int a0 = 0; a0 < ADIM; a0 += 4) {
        float4 xv = *(const float4*)(xr + a0);
#pragma unroll
        for (int u = 0; u < 4; ++u) {
            double xd = (double)((&xv.x)[u]);
            const double* wp = W64T + (a0 + u) * NG + cb;  // uniform -> broadcast
#pragma unroll
            for (int j = 0; j < 10; ++j) acc[j] = fma(wp[j], xd, acc[j]);
        }
    }
    int trow = (int)(row & (TT - 1));
    float* op = X32 + row * NG + cb;
#pragma unroll
    for (int j = 0; j < 10; ++j) {
        double a0j = ADD0[cb + j], a1j = ADD1[cb + j];
        op[j] = (float)(acc[j] + (trow == 0 ? a0j : a1j));   // round once
    }
}

// ---------------- sequential recurrence: one wave per batch ----------------
// QUAD layout: lane 4m+j holds gate j (i,f,g,o) of embedding m (m<10).
// All 4 lanes of quad m compute IDENTICAL c,h (quad-redundant) — required by
// the ror4/ror8 argmax reduce (R3 bug) AND by the ballot index extraction.
// Full-f32 step (ref is numpy f32; R9 proved margins tolerate f32 noise).
// Argmax is EXACT over our f32 h: sortable-u32 key (no index packed), DPP
// v_max_u32 reduce, winner = ctz(ballot(key==max))>>2 (ties -> lowest m =
// numpy first-index). Branchless stores: no exec churn near DPP (R8).
// 1 wave/SIMD (R8: co-residency hurts wall); all on VALU (R5: SALU 2x worse).
__global__ __launch_bounds__(64) void recur_kernel(
        const float* __restrict__ X32,
        const float* __restrict__ W_hh, const float* __restrict__ Etab32,
        char* __restrict__ ws) {
    const int k = threadIdx.x;
    const int b = blockIdx.x;
    const int j = k & 3;                 // gate type 0..3 = i,f,g,o
    const int m = k >> 2;                // embedding index (valid < 10)
    const bool valid = (k < NG);
    const int col = valid ? (j * 10 + m) : (NG - 1);
    const bool isg = (j == 2);

    const float LOG2E = 1.44269504088896340736f;
    // i/f/o: e1 = 2^{-g*log2e} -> act = 1/(1+e1)          (amul=1, aadd=0)
    // g:     e1 = 2^{-2g*log2e} -> act = 2/(1+e1) - 1     (amul=2, aadd=-1)
    const float Lg   = isg ? (-2.0f * LOG2E) : (-LOG2E);
    const float amul = isg ? 2.0f : 1.0f;
    const float aadd = isg ? -1.0f : 0.0f;
    const float L2   = -2.0f * LOG2E;    // tanh|c|: 2/(1+2^{-2|c|log2e}) - 1

    float whh[NE];
#pragma unroll
    for (int mm = 0; mm < NE; ++mm) whh[mm] = W_hh[col * NE + mm];
    float etab[NE];
#pragma unroll
    for (int i = 0; i < NE; ++i) etab[i] = Etab32[i * NG + col];

    const float* Xb = X32 + (long)b * TT * NG;

    // branchless-store setup: every lane stores 4B each step.
    const bool is_h = ((k & 3) == 0) && valid;   // lanes 4m, m<10
    const bool is_i = (k == NG);                 // lane 40
    unsigned voff = is_h ? (unsigned)(OFF_H + ((unsigned)b * TT * NE + m) * 4u)
                  : is_i ? (unsigned)(OFF_IDX + (unsigned)b * TT * 4u)
                         : (unsigned)OFF_DUMP;
    const unsigned vstep = is_h ? (unsigned)(NE * 4) : is_i ? 4u : 0u;

    const unsigned vmask = valid ? 0xFFFFFFFFu : 0u;   // key kill for k>=40

    // prefetch ring depth 4 (t+4 overrun stays inside allocated ws slack)
    float xs0 = Xb[0 * NG + col];
    float xs1 = Xb[1 * NG + col];
    float xs2 = Xb[2 * NG + col];
    float xs3 = Xb[3 * NG + col];

    float ha[NE];
#pragma unroll
    for (int mm = 0; mm < NE; ++mm) ha[mm] = 0.0f;
    float c = 0.0f, esel = 0.0f;

    auto step = [&](float& xslot, int t) {
        float xg = xslot;
        xslot = Xb[(t + 4) * NG + col];

        // gate = xg(+bias+qb folded in gemm) + esel + <h_prev, W_hh[col,:]>
        float p0 = fmaf(ha[1], whh[1], ha[0] * whh[0]);
        float p1 = fmaf(ha[3], whh[3], ha[2] * whh[2]);
        float p2 = fmaf(ha[5], whh[5], ha[4] * whh[4]);
        float p3 = fmaf(ha[7], whh[7], ha[6] * whh[6]);
        float p4 = fmaf(ha[9], whh[9], ha[8] * whh[8]);
        float dotE = ((p0 + p1) + (p2 + p3)) + (p4 + esel);
        float g32 = xg + dotE;

        float e1 = fexp2(g32 * Lg);          // no range reduction: |g|<~10
        float r1 = frcp1(1.0f + e1);
        float act = fmaf(amul, r1, aadd);

        // quad gather: broadcast ALL FOUR gates (quad-redundant c,h required)
        float fiv = dpp_mov_f32<0x00>(act);
        float ffv = dpp_mov_f32<0x55>(act);
        float fgv = dpp_mov_f32<0xAA>(act);
        float fov = dpp_mov_f32<0xFF>(act);
        c = fmaf(ffv, c, fiv * fgv);         // bit-identical across quad

        float e2 = fexp2(fabsf(c) * L2);     // 2^{-2|c|log2e} in (0,1]
        float r2 = frcp1(1.0f + e2);
        float th = fmaf(2.0f, r2, -1.0f);    // tanh(|c|) in [0,1)
        float habs = fov * th;               // >= 0
        int hI = __float_as_int(habs) | (__float_as_int(c) & 0x80000000);

        // EXACT argmax: sortable-u32 key, DPP u32 max reduce, ballot+ctz.
        int smsk = hI >> 31;
        unsigned key0 = ((unsigned)(hI ^ (smsk | (int)0x80000000))) & vmask;
        unsigned kr = umax2(key0, dpp_mov_u32<0x124, 0xF>(key0));  // ror:4
        kr = umax2(kr, dpp_mov_u32<0x128, 0xF>(kr));               // ror:8
        kr = umax2(kr, dpp_mov_u32<0x142, 0xA>(kr));               // bcast15
        kr = umax2(kr, dpp_mov_u32<0x143, 0xC>(kr));               // bcast31
        unsigned sMax = (unsigned)__builtin_amdgcn_readlane((int)kr, 32);
        unsigned long long ball = __ballot(key0 == sMax);
        int s_idx = ((int)__builtin_ctzll(ball)) >> 2;   // lowest lane -> m

        // branchless store: all 64 lanes store 4B (h / idx / dump)
        int val = is_h ? hI : s_idx;
        *(int*)(ws + voff) = val;
        voff += vstep;

        // broadcast h into SGPR-resident ha[] (quad-lane 4m per embedding)
#pragma unroll
        for (int mm = 0; mm < NE; ++mm)
            ha[mm] = __int_as_float(__builtin_amdgcn_readlane(hI, 4 * mm));

        // esel = etab[s_idx]: 4-level bit-tree select on VALU (f32)
        float a0 = (s_idx & 1) ? etab[1] : etab[0];
        float a1 = (s_idx & 1) ? etab[3] : etab[2];
        float a2 = (s_idx & 1) ? etab[5] : etab[4];
        float a3 = (s_idx & 1) ? etab[7] : etab[6];
        float a4 = (s_idx & 1) ? etab[9] : etab[8];
        float b0 = (s_idx & 2) ? a1 : a0;
        float b1 = (s_idx & 2) ? a3 : a2;
        float c0 = (s_idx & 4) ? b1 : b0;
        esel = (s_idx & 8) ? a4 : c0;
    };

    for (int t = 0; t < TT; t += 4) {
        step(xs0, t);
        step(xs1, t + 1);
        step(xs2, t + 2);
        step(xs3, t + 3);
    }
}

// ---------------- deferred: embs gather + NLL partial sums ----------------
__global__ __launch_bounds__(256) void tail_kernel(
        const float* __restrict__ h_ws, const int* __restrict__ idx_ws,
        const int* __restrict__ inds, const float* __restrict__ codebook,
        float* __restrict__ out_embs, double* __restrict__ partials) {
    int i = blockIdx.x * 256 + threadIdx.x;   // 512*256 == 131072 exactly
    int idx = idx_ws[i];
    out_embs[i * 3 + 0] = codebook[idx * 3 + 0];
    out_embs[i * 3 + 1] = codebook[idx * 3 + 1];
    out_embs[i * 3 + 2] = codebook[idx * 3 + 2];

    const float* hp = h_ws + (long)i * NE;
    double hv[NE];
#pragma unroll
    for (int mm = 0; mm < NE; ++mm) hv[mm] = (double)hp[mm];
    double mx = hv[0];
#pragma unroll
    for (int mm = 1; mm < NE; ++mm) mx = fmax(mx, hv[mm]);
    double sdn = 0.0;
#pragma unroll
    for (int mm = 0; mm < NE; ++mm) sdn += exp(hv[mm] - mx);
    int ind = inds[i];
    double picked = (double)hp[ind] - (mx + log(sdn));

    __shared__ double red[256];
    red[threadIdx.x] = picked;
    __syncthreads();
    for (int st = 128; st > 0; st >>= 1) {
        if (threadIdx.x < st) red[threadIdx.x] += red[threadIdx.x + st];
        __syncthreads();
    }
    if (threadIdx.x == 0) partials[blockIdx.x] = red[0];
}

__global__ __launch_bounds__(256) void final_kernel(
        const double* __restrict__ partials, float* __restrict__ out_loss) {
    __shared__ double red[256];
    red[threadIdx.x] = partials[threadIdx.x] + partials[threadIdx.x + 256];
    __syncthreads();
    for (int st = 128; st > 0; st >>= 1) {
        if (threadIdx.x < st) red[threadIdx.x] += red[threadIdx.x + st];
        __syncthreads();
    }
    if (threadIdx.x == 0)
        out_loss[0] = (float)(-red[0] / (double)(BB * TT));
}

extern "C" void kernel_launch(void* const* d_in, const int* in_sizes, int n_in,
                              void* d_out, int out_size, void* d_ws, size_t ws_size,
                              hipStream_t stream) {
    const float* hs       = (const float*)d_in[0];
    const int*   inds     = (const int*)d_in[1];
    const float* codebook = (const float*)d_in[2];
    const float* W_ih     = (const float*)d_in[3];
    const float* W_hh     = (const float*)d_in[4];
    const float* b_ih     = (const float*)d_in[5];
    const float* b_hh     = (const float*)d_in[6];
    const float* qs_W     = (const float*)d_in[7];
    const float* qs_b     = (const float*)d_in[8];
    float* out = (float*)d_out;

    char* ws = (char*)d_ws;
    float*  X32   = (float*)(ws + OFF_X64);
    double* W64T  = (double*)(ws + OFF_W64T);
    float*  Etab32= (float*)(ws + OFF_ETAB);
    double* ADD0  = (double*)(ws + OFF_ADD0);
    double* ADD1  = (double*)(ws + OFF_ADD1);
    float*  h_ws  = (float*)(ws + OFF_H);
    int*    idx_ws= (int*)(ws + OFF_IDX);
    double* part  = (double*)(ws + OFF_PART);

    setup_kernel<<<61, 256, 0, stream>>>(W_ih, codebook, qs_W, qs_b, b_ih, b_hh,
                                         W64T, Etab32, ADD0, ADD1);
    gemm_kernel<<<2048, 256, 0, stream>>>(hs, W64T, ADD0, ADD1, X32);
    recur_kernel<<<BB, 64, 0, stream>>>(X32, W_hh, Etab32, ws);
    tail_kernel<<<512, 256, 0, stream>>>(h_ws, idx_ws, inds, codebook, out, part);
    final_kernel<<<1, 256, 0, stream>>>(part, out + (size_t)BB * TT * HD);
}

// Round 12
// 570.236 us; speedup vs baseline: 2.7009x; 1.0441x over previous
//
#include <hip/hip_runtime.h>
#include <math.h>

#define BB 64
#define TT 2048
#define ADIM 384
#define NE 10    // num_embeddings == LSTM hidden
#define NG 40    // 4*NE gates
#define HD 3     // hidden_dim (codebook width)

// ---------------- workspace layout (bytes) ----------------
#define OFF_X32   0ULL                        // BB*TT*NG*4 = 20971520 (+slack)
#define OFF_ETAB  (41943040ULL + 122880ULL)   // NE*NG*4 (f32, codebook@M + bias + qb)
#define OFF_BIAS0 (OFF_ETAB + 3200ULL)        // NG*4 (f32 bias, t==0 esel seed)
#define OFF_H     (OFF_BIAS0 + 320ULL)        // BB*TT*NE*4 = 5242880
#define OFF_IDX   (OFF_H + 5242880ULL)        // BB*TT*4 = 524288
#define OFF_PART  (OFF_IDX + 524288ULL)       // 512*8
#define OFF_DUMP  (OFF_PART + 4096ULL)        // dump word for garbage lanes

// ---------------- fast helpers ----------------
__device__ __forceinline__ float fexp2(float x) {   // HW 2^x, ~1 ulp
    float r;
    asm("v_exp_f32 %0, %1" : "=v"(r) : "v"(x));
    return r;
}
__device__ __forceinline__ float frcp(float d) {    // HW rcp, ~1 ulp
    float r;
    asm("v_rcp_f32 %0, %1" : "=v"(r) : "v"(d));
    return r;
}

template<int CTRL>
__device__ __forceinline__ float dpp_mov_f32(float x) {
    int v = __float_as_int(x);
    v = __builtin_amdgcn_update_dpp(v, v, CTRL, 0xF, 0xF, true);
    return __int_as_float(v);
}
template<int CTRL, int RMASK>
__device__ __forceinline__ unsigned dpp_mov_u32(unsigned x) {
    int v = __builtin_amdgcn_update_dpp((int)x, (int)x, CTRL, RMASK, 0xF, true);
    return (unsigned)v;
}
__device__ __forceinline__ unsigned umax2(unsigned a, unsigned b) {
    return a > b ? a : b;
}

// ---------------- setup: EtabB = codebook@M + bias + qb; bias0 -------------
__global__ __launch_bounds__(64) void setup_kernel(
        const float* __restrict__ W_ih, const float* __restrict__ codebook,
        const float* __restrict__ qs_W, const float* __restrict__ qs_b,
        const float* __restrict__ b_ih, const float* __restrict__ b_hh,
        float* __restrict__ EtabB, float* __restrict__ BIAS0) {
    int k = threadIdx.x;
    if (k >= NG) return;
    double M0 = 0, M1 = 0, M2 = 0, qb = 0;
    for (int a = 0; a < ADIM; ++a) {
        double w = (double)W_ih[k * ADIM + a];
        M0 = fma(w, (double)qs_W[a * HD + 0], M0);
        M1 = fma(w, (double)qs_W[a * HD + 1], M1);
        M2 = fma(w, (double)qs_W[a * HD + 2], M2);
        qb = fma(w, (double)qs_b[a], qb);
    }
    double bias = (double)b_ih[k] + (double)b_hh[k];
    for (int i = 0; i < NE; ++i) {
        double e = bias + qb;                // t>0 esel includes bias + qb
        e = fma((double)codebook[i * HD + 0], M0, e);
        e = fma((double)codebook[i * HD + 1], M1, e);
        e = fma((double)codebook[i * HD + 2], M2, e);
        EtabB[i * NG + k] = (float)e;
    }
    BIAS0[k] = (float)bias;                  // t==0 esel seed (no qs path)
}

// ---------------- X = hs @ W_ih.T  (f32, dual accumulator) -----------------
__global__ __launch_bounds__(256) void gemm_kernel(
        const float* __restrict__ hs, const float* __restrict__ W_ih,
        float* __restrict__ X32) {
    int lane = threadIdx.x & 63;
    int wv = threadIdx.x >> 6;
    int cb = __builtin_amdgcn_readfirstlane(wv * 10);   // wave-uniform col base
    long row = (long)blockIdx.x * 64 + lane;            // < 131072
    const float* xr = hs + row * ADIM;
    float accA[10], accB[10];
#pragma unroll
    for (int j = 0; j < 10; ++j) { accA[j] = 0.0f; accB[j] = 0.0f; }
    for (int a0 = 0; a0 < ADIM; a0 += 4) {
        float4 xv = *(const float4*)(xr + a0);
#pragma unroll
        for (int j = 0; j < 10; ++j) {
            // uniform address -> scalar broadcast load
            float4 wv4 = *(const float4*)(W_ih + (cb + j) * ADIM + a0);
            accA[j] = fmaf(wv4.x, xv.x, accA[j]);
            accA[j] = fmaf(wv4.y, xv.y, accA[j]);
            accB[j] = fmaf(wv4.z, xv.z, accB[j]);
            accB[j] = fmaf(wv4.w, xv.w, accB[j]);
        }
    }
    float* op = X32 + row * NG + cb;
#pragma unroll
    for (int j = 0; j < 10; ++j) op[j] = accA[j] + accB[j];
}

// ---------------- sequential recurrence: one wave per batch ----------------
// QUAD layout: lane 4m+j holds gate j (i,f,g,o) of embedding m (m<10).
// All 4 lanes of quad m compute IDENTICAL c,h (quad-redundant). The DPP
// argmax reduce (ror4+ror8 then bcast15/31) combines each lane only with
// its mod-4 congruence class — keys MUST live on all 4 lanes of each quad
// or the bcast path forwards zeros (R3 and R11 both failed exactly here).
// The i-gate broadcast IS the key-replication step. Do not remove it.
// Full-f32 step; argmax exact over our f32 h (sortable-u32 keys, ballot
// first-index ties). Raw v_rcp_f32 (no NR). Bias+qb folded into esel.
// 1 wave/SIMD (R8); all on VALU (R5); branchless stores (R8).
__global__ __launch_bounds__(64) void recur_kernel(
        const float* __restrict__ X32,
        const float* __restrict__ W_hh, const float* __restrict__ EtabB,
        const float* __restrict__ BIAS0, char* __restrict__ ws) {
    const int k = threadIdx.x;
    const int b = blockIdx.x;
    const int j = k & 3;                 // gate type 0..3 = i,f,g,o
    const int m = k >> 2;                // embedding index (valid < 10)
    const bool valid = (k < NG);
    const int col = valid ? (j * 10 + m) : (NG - 1);
    const bool isg = (j == 2);

    const float LOG2E = 1.44269504088896340736f;
    const float Lg   = isg ? (-2.0f * LOG2E) : (-LOG2E);
    const float amul = isg ? 2.0f : 1.0f;
    const float aadd = isg ? -1.0f : 0.0f;
    const float L2   = -2.0f * LOG2E;    // tanh|c|: 2/(1+2^{-2|c|log2e}) - 1

    float whh[NE];
#pragma unroll
    for (int mm = 0; mm < NE; ++mm) whh[mm] = W_hh[col * NE + mm];
    float etab[NE];
#pragma unroll
    for (int i = 0; i < NE; ++i) etab[i] = EtabB[i * NG + col];

    const float* Xb = X32 + (long)b * TT * NG;

    // branchless-store setup: every lane stores 4B each step.
    const bool is_h = ((k & 3) == 0) && valid;   // lanes 4m, m<10
    const bool is_i = (k == NG);                 // lane 40
    unsigned voff = is_h ? (unsigned)(OFF_H + ((unsigned)b * TT * NE + m) * 4u)
                  : is_i ? (unsigned)(OFF_IDX + (unsigned)b * TT * 4u)
                         : (unsigned)OFF_DUMP;
    const unsigned vstep = is_h ? (unsigned)(NE * 4) : is_i ? 4u : 0u;

    const unsigned vmask = valid ? 0xFFFFFFFFu : 0u;   // keys on ALL 40 lanes

    // prefetch ring depth 4 (overrun reads stay inside allocated ws slack)
    float xs0 = Xb[0 * NG + col];
    float xs1 = Xb[1 * NG + col];
    float xs2 = Xb[2 * NG + col];
    float xs3 = Xb[3 * NG + col];

    float ha[NE];
#pragma unroll
    for (int mm = 0; mm < NE; ++mm) ha[mm] = 0.0f;
    float c = 0.0f;
    float esel = BIAS0[col];             // t==0: gate = x + bias (no qs)

    auto step = [&](float& xslot, int t) {
        float xg = xslot;
        xslot = Xb[(t + 4) * NG + col];

        // gate = xg + esel(bias/etab) + <h_prev, W_hh[col,:]>
        float p0 = fmaf(ha[1], whh[1], ha[0] * whh[0]);
        float p1 = fmaf(ha[3], whh[3], ha[2] * whh[2]);
        float p2 = fmaf(ha[5], whh[5], ha[4] * whh[4]);
        float p3 = fmaf(ha[7], whh[7], ha[6] * whh[6]);
        float p4 = fmaf(ha[9], whh[9], ha[8] * whh[8]);
        float dotE = ((p0 + p1) + (p2 + p3)) + (p4 + esel);
        float g32 = xg + dotE;

        float e1 = fexp2(g32 * Lg);          // no range reduction: |g|<~10
        float r1 = frcp(1.0f + e1);
        float act = fmaf(amul, r1, aadd);

        // quad gather: broadcast ALL FOUR gates (quad-redundant c,h REQUIRED
        // by the argmax reduce — see header comment; R3/R11 failure mode)
        float fiv = dpp_mov_f32<0x00>(act);
        float ffv = dpp_mov_f32<0x55>(act);
        float fgv = dpp_mov_f32<0xAA>(act);
        float fov = dpp_mov_f32<0xFF>(act);
        c = fmaf(ffv, c, fiv * fgv);         // bit-identical across quad

        float e2 = fexp2(fabsf(c) * L2);     // 2^{-2|c|log2e} in (0,1]
        float r2 = frcp(1.0f + e2);
        float th = fmaf(2.0f, r2, -1.0f);    // tanh(|c|) in [0,1)
        float habs = fov * th;               // >= 0
        int hI = __float_as_int(habs) | (__float_as_int(c) & 0x80000000);

        // EXACT argmax: sortable-u32 key on all valid lanes, DPP u32 max
        // reduce, ballot+ctz (ties -> lowest lane -> lowest m = numpy)
        int smsk = hI >> 31;
        unsigned key0 = ((unsigned)(hI ^ (smsk | (int)0x80000000))) & vmask;
        unsigned kr = umax2(key0, dpp_mov_u32<0x124, 0xF>(key0));  // ror:4
        kr = umax2(kr, dpp_mov_u32<0x128, 0xF>(kr));               // ror:8
        kr = umax2(kr, dpp_mov_u32<0x142, 0xA>(kr));               // bcast15
        kr = umax2(kr, dpp_mov_u32<0x143, 0xC>(kr));               // bcast31
        unsigned sMax = (unsigned)__builtin_amdgcn_readlane((int)kr, 32);
        unsigned long long ball = __ballot(key0 == sMax);
        int s_idx = ((int)__builtin_ctzll(ball)) >> 2;   // lowest lane -> m

        // branchless store: all 64 lanes store 4B (h / idx / dump)
        int val = is_h ? hI : s_idx;
        *(int*)(ws + voff) = val;
        voff += vstep;

        // broadcast h into SGPR-resident ha[] (quad-lane 4m per embedding)
#pragma unroll
        for (int mm = 0; mm < NE; ++mm)
            ha[mm] = __int_as_float(__builtin_amdgcn_readlane(hI, 4 * mm));

        // esel = etab[s_idx] (includes bias+qb): 4-level bit-tree on VALU
        float a0 = (s_idx & 1) ? etab[1] : etab[0];
        float a1 = (s_idx & 1) ? etab[3] : etab[2];
        float a2 = (s_idx & 1) ? etab[5] : etab[4];
        float a3 = (s_idx & 1) ? etab[7] : etab[6];
        float a4 = (s_idx & 1) ? etab[9] : etab[8];
        float b0 = (s_idx & 2) ? a1 : a0;
        float b1 = (s_idx & 2) ? a3 : a2;
        float c0 = (s_idx & 4) ? b1 : b0;
        esel = (s_idx & 8) ? a4 : c0;
    };

    for (int t = 0; t < TT; t += 4) {
        step(xs0, t);
        step(xs1, t + 1);
        step(xs2, t + 2);
        step(xs3, t + 3);
    }
}

// ---------------- deferred: embs gather + NLL partial sums ----------------
__global__ __launch_bounds__(256) void tail_kernel(
        const float* __restrict__ h_ws, const int* __restrict__ idx_ws,
        const int* __restrict__ inds, const float* __restrict__ codebook,
        float* __restrict__ out_embs, double* __restrict__ partials) {
    int i = blockIdx.x * 256 + threadIdx.x;   // 512*256 == 131072 exactly
    int idx = idx_ws[i];
    out_embs[i * 3 + 0] = codebook[idx * 3 + 0];
    out_embs[i * 3 + 1] = codebook[idx * 3 + 1];
    out_embs[i * 3 + 2] = codebook[idx * 3 + 2];

    const float* hp = h_ws + (long)i * NE;
    double hv[NE];
#pragma unroll
    for (int mm = 0; mm < NE; ++mm) hv[mm] = (double)hp[mm];
    double mx = hv[0];
#pragma unroll
    for (int mm = 1; mm < NE; ++mm) mx = fmax(mx, hv[mm]);
    double sdn = 0.0;
#pragma unroll
    for (int mm = 0; mm < NE; ++mm) sdn += exp(hv[mm] - mx);
    int ind = inds[i];
    double picked = (double)hp[ind] - (mx + log(sdn));

    __shared__ double red[256];
    red[threadIdx.x] = picked;
    __syncthreads();
    for (int st = 128; st > 0; st >>= 1) {
        if (threadIdx.x < st) red[threadIdx.x] += red[threadIdx.x + st];
        __syncthreads();
    }
    if (threadIdx.x == 0) partials[blockIdx.x] = red[0];
}

__global__ __launch_bounds__(256) void final_kernel(
        const double* __restrict__ partials, float* __restrict__ out_loss) {
    __shared__ double red[256];
    red[threadIdx.x] = partials[threadIdx.x] + partials[threadIdx.x + 256];
    __syncthreads();
    for (int st = 128; st > 0; st >>= 1) {
        if (threadIdx.x < st) red[threadIdx.x] += red[threadIdx.x + st];
        __syncthreads();
    }
    if (threadIdx.x == 0)
        out_loss[0] = (float)(-red[0] / (double)(BB * TT));
}

extern "C" void kernel_launch(void* const* d_in, const int* in_sizes, int n_in,
                              void* d_out, int out_size, void* d_ws, size_t ws_size,
                              hipStream_t stream) {
    const float* hs       = (const float*)d_in[0];
    const int*   inds     = (const int*)d_in[1];
    const float* codebook = (const float*)d_in[2];
    const float* W_ih     = (const float*)d_in[3];
    const float* W_hh     = (const float*)d_in[4];
    const float* b_ih     = (const float*)d_in[5];
    const float* b_hh     = (const float*)d_in[6];
    const float* qs_W     = (const float*)d_in[7];
    const float* qs_b     = (const float*)d_in[8];
    float* out = (float*)d_out;

    char* ws = (char*)d_ws;
    float*  X32   = (float*)(ws + OFF_X32);
    float*  EtabB = (float*)(ws + OFF_ETAB);
    float*  BIAS0 = (float*)(ws + OFF_BIAS0);
    float*  h_ws  = (float*)(ws + OFF_H);
    int*    idx_ws= (int*)(ws + OFF_IDX);
    double* part  = (double*)(ws + OFF_PART);

    setup_kernel<<<1, 64, 0, stream>>>(W_ih, codebook, qs_W, qs_b, b_ih, b_hh,
                                       EtabB, BIAS0);
    gemm_kernel<<<2048, 256, 0, stream>>>(hs, W_ih, X32);
    recur_kernel<<<BB, 64, 0, stream>>>(X32, W_hh, EtabB, BIAS0, ws);
    tail_kernel<<<512, 256, 0, stream>>>(h_ws, idx_ws, inds, codebook, out, part);
    final_kernel<<<1, 256, 0, stream>>>(part, out + (size_t)BB * TT * HD);
}